// Round 1
// baseline (1384.442 us; speedup 1.0000x reference)
//
#include <hip/hip_runtime.h>
#include <math.h>

// Problem constants (B=4,S=2048,D=1024,H=2048,E=8, top-2)
#define T_TOKENS 8192
#define DIM      1024
#define HDIM     2048
#define NEXP     8
#define NASSIGN  16384   // T_TOKENS * 2

typedef __attribute__((ext_vector_type(8))) short short8;
typedef __attribute__((ext_vector_type(4))) float floatx4;

__device__ __forceinline__ unsigned short f2bf(float f) {
  unsigned u = __float_as_uint(f);
  u += 0x7fffu + ((u >> 16) & 1u);   // RNE
  return (unsigned short)(u >> 16);
}
__device__ __forceinline__ float bf2f(unsigned short h) {
  return __uint_as_float(((unsigned)h) << 16);
}

// ---------------- convert x fp32 -> bf16 ----------------
__global__ void convert_x_kernel(const float* __restrict__ in,
                                 unsigned short* __restrict__ out, long n) {
  long i = ((long)blockIdx.x * blockDim.x + threadIdx.x) * 4;
  if (i >= n) return;
  float4 v = *(const float4*)(in + i);
  ushort4 o;
  o.x = f2bf(v.x); o.y = f2bf(v.y); o.z = f2bf(v.z); o.w = f2bf(v.w);
  *(ushort4*)(out + i) = o;
}

// ------- transpose + convert: in [E][R][C] fp32 -> out [E][C][R] bf16 -------
__global__ void transpose_convert_kernel(const float* __restrict__ in,
                                         unsigned short* __restrict__ out,
                                         int R, int C) {
  __shared__ float tile[32][33];
  int e = blockIdx.z;
  int c0 = blockIdx.x * 32, r0 = blockIdx.y * 32;
  const float* inp = in + (long)e * R * C;
  unsigned short* outp = out + (long)e * R * C;
  int tx = threadIdx.x, ty = threadIdx.y;  // 32 x 8
  #pragma unroll
  for (int i = 0; i < 32; i += 8)
    tile[ty + i][tx] = inp[(long)(r0 + ty + i) * C + c0 + tx];
  __syncthreads();
  #pragma unroll
  for (int i = 0; i < 32; i += 8)
    outp[(long)(c0 + ty + i) * R + r0 + tx] = f2bf(tile[tx][ty + i]);
}

// ---------------- router: fp32, one wave per token ----------------
__global__ __launch_bounds__(256) void router_kernel(
    const float* __restrict__ x, const float* __restrict__ Wr,
    const float* __restrict__ br,
    int* __restrict__ topk_i, float* __restrict__ topk_w,
    int* __restrict__ counts, float* __restrict__ probs_sum) {
  __shared__ float sW[NEXP * DIM];  // transposed: sW[e*1024 + d], 32 KB
  int tid = threadIdx.x;
  for (int i = tid; i < NEXP * DIM; i += 256) {
    int e = i >> 10, d = i & 1023;
    sW[i] = Wr[d * NEXP + e];
  }
  __syncthreads();
  int wid = tid >> 6, lane = tid & 63;
  int t = blockIdx.x * 4 + wid;
  const float* xp = x + (long)t * DIM;
  float acc[NEXP];
  #pragma unroll
  for (int e = 0; e < NEXP; e++) acc[e] = 0.f;
  #pragma unroll
  for (int i = 0; i < 16; i++) {
    float v = xp[i * 64 + lane];
    #pragma unroll
    for (int e = 0; e < NEXP; e++) acc[e] += v * sW[e * DIM + i * 64 + lane];
  }
  #pragma unroll
  for (int e = 0; e < NEXP; e++) {
    #pragma unroll
    for (int off = 32; off; off >>= 1) acc[e] += __shfl_xor(acc[e], off, 64);
  }
  if (lane == 0) {
    float l[NEXP];
    #pragma unroll
    for (int e = 0; e < NEXP; e++) l[e] = acc[e] + br[e];
    float mx = l[0];
    #pragma unroll
    for (int e = 1; e < NEXP; e++) mx = fmaxf(mx, l[e]);
    float p[NEXP], s = 0.f;
    #pragma unroll
    for (int e = 0; e < NEXP; e++) { p[e] = __expf(l[e] - mx); s += p[e]; }
    float inv = 1.f / s;
    #pragma unroll
    for (int e = 0; e < NEXP; e++) p[e] *= inv;
    // top-2, lowest index wins ties (matches lax.top_k)
    int i1 = 0;
    #pragma unroll
    for (int e = 1; e < NEXP; e++) if (l[e] > l[i1]) i1 = e;
    int i2 = (i1 == 0) ? 1 : 0;
    #pragma unroll
    for (int e = 0; e < NEXP; e++)
      if (e != i1 && l[e] > l[i2]) i2 = e;
    float s2 = p[i1] + p[i2];
    s2 = fmaxf(s2, 1e-9f);
    topk_i[2 * t] = i1; topk_i[2 * t + 1] = i2;
    topk_w[2 * t] = p[i1] / s2; topk_w[2 * t + 1] = p[i2] / s2;
    atomicAdd(&counts[i1], 1);
    atomicAdd(&counts[i2], 1);
    #pragma unroll
    for (int e = 0; e < NEXP; e++) atomicAdd(&probs_sum[e], p[e]);
  }
}

// ---------------- scan counts -> offsets, compute aux loss ----------------
__global__ void scan_aux_kernel(const int* __restrict__ counts,
                                int* __restrict__ offsets,
                                const float* __restrict__ probs_sum,
                                float* __restrict__ aux_out) {
  if (threadIdx.x != 0 || blockIdx.x != 0) return;
  int total = 0;
  for (int e = 0; e < NEXP; e++) total += counts[e];
  int off = 0; float aux = 0.f;
  float inv_total = 1.f / (float)(total > 0 ? total : 1);
  for (int e = 0; e < NEXP; e++) {
    offsets[e] = off; off += counts[e];
    float importance = probs_sum[e] / (float)T_TOKENS;
    float load = (float)counts[e] * inv_total;
    aux += importance * load;
  }
  *aux_out = (float)NEXP * aux;
}

// ---------------- fill per-expert token lists ----------------
__global__ void fill_kernel(const int* __restrict__ topk_i,
                            const int* __restrict__ offsets,
                            int* __restrict__ fillc,
                            int* __restrict__ token_list,
                            int* __restrict__ slot_of) {
  int t = blockIdx.x * 256 + threadIdx.x;
  if (t >= T_TOKENS) return;
  #pragma unroll
  for (int k = 0; k < 2; k++) {
    int e = topk_i[2 * t + k];
    int pos = atomicAdd(&fillc[e], 1);
    int slot = offsets[e] + pos;
    token_list[slot] = t;
    slot_of[2 * t + k] = slot;
  }
}

// ---------------- grouped GEMM: 128x128 tile, bf16 MFMA ----------------
// C[r][n] = sum_k A[r][k] * B[k][n]  (+bias[n], optional exact-GELU)
// A rows gathered via token_list (GATHER) or direct (rowbase + r).
// BT is [E][N][K] (pre-transposed) so B-fragments are K-contiguous.
template<bool GELU, bool GATHER>
__global__ __launch_bounds__(256, 2) void gemm_kernel(
    const unsigned short* __restrict__ Abase,  // bf16 [*, K]
    const unsigned short* __restrict__ BT,     // bf16 [E][N][K]
    const float* __restrict__ bias,            // fp32 [E][N]
    unsigned short* __restrict__ Cout,         // bf16 [NASSIGN][N]
    const int* __restrict__ counts,
    const int* __restrict__ offsets,
    const int* __restrict__ token_list,
    int K, int N) {
  int e = blockIdx.z;
  int cnt = counts[e];
  int mtile = blockIdx.y;
  if (mtile * 128 >= cnt) return;
  int rowbase = offsets[e];
  int n0 = blockIdx.x * 128;
  int tid = threadIdx.x;

  __shared__ unsigned short As[128][72];
  __shared__ unsigned short Bs[128][72];

  // staging map: thread -> (row = tid>>1, k half = (tid&1)*32)
  int sr = tid >> 1;
  int sk = (tid & 1) * 32;
  int r_local = mtile * 128 + sr;
  long arow;
  if (GATHER) {
    int t = (r_local < cnt) ? token_list[rowbase + r_local] : 0;
    arow = (long)t * K;
  } else {
    int rr = rowbase + r_local;
    if (rr > NASSIGN - 1) rr = NASSIGN - 1;
    arow = (long)rr * K;
  }
  const unsigned short* Ap = Abase + arow + sk;
  const unsigned short* Bp = BT + ((long)e * N + (n0 + sr)) * K + sk;

  int wid = tid >> 6, lane = tid & 63;
  int wr = (wid >> 1) * 64, wc = (wid & 1) * 64;
  int lr = lane & 15, lq = lane >> 4;

  floatx4 zero = {0.f, 0.f, 0.f, 0.f};
  floatx4 acc[4][4];
  #pragma unroll
  for (int im = 0; im < 4; im++)
    #pragma unroll
    for (int in = 0; in < 4; in++) acc[im][in] = zero;

  for (int k0 = 0; k0 < K; k0 += 64) {
    const int4* ga = (const int4*)(Ap + k0);
    const int4* gb = (const int4*)(Bp + k0);
    int4 a0 = ga[0], a1 = ga[1], a2 = ga[2], a3 = ga[3];
    int4 b0 = gb[0], b1 = gb[1], b2 = gb[2], b3 = gb[3];
    *(int4*)&As[sr][sk + 0]  = a0;
    *(int4*)&As[sr][sk + 8]  = a1;
    *(int4*)&As[sr][sk + 16] = a2;
    *(int4*)&As[sr][sk + 24] = a3;
    *(int4*)&Bs[sr][sk + 0]  = b0;
    *(int4*)&Bs[sr][sk + 8]  = b1;
    *(int4*)&Bs[sr][sk + 16] = b2;
    *(int4*)&Bs[sr][sk + 24] = b3;
    __syncthreads();
    #pragma unroll
    for (int kk = 0; kk < 64; kk += 32) {
      short8 af[4], bf[4];
      #pragma unroll
      for (int im = 0; im < 4; im++)
        af[im] = *(const short8*)&As[wr + im * 16 + lr][kk + lq * 8];
      #pragma unroll
      for (int in = 0; in < 4; in++)
        bf[in] = *(const short8*)&Bs[wc + in * 16 + lr][kk + lq * 8];
      #pragma unroll
      for (int im = 0; im < 4; im++)
        #pragma unroll
        for (int in = 0; in < 4; in++)
          acc[im][in] = __builtin_amdgcn_mfma_f32_16x16x32_bf16(
              af[im], bf[in], acc[im][in], 0, 0, 0);
    }
    __syncthreads();
  }

  // epilogue: D[row=lq*4+j][col=lr] per fragment
  float bv[4];
  #pragma unroll
  for (int in = 0; in < 4; in++)
    bv[in] = bias[(long)e * N + n0 + wc + in * 16 + lr];
  #pragma unroll
  for (int im = 0; im < 4; im++) {
    int rbase = mtile * 128 + wr + im * 16 + lq * 4;
    #pragma unroll
    for (int j = 0; j < 4; j++) {
      int r = rbase + j;
      if (r < cnt) {
        long rowoff = (long)(rowbase + r) * N;
        #pragma unroll
        for (int in = 0; in < 4; in++) {
          int col = n0 + wc + in * 16 + lr;
          float v = acc[im][in][j] + bv[in];
          if (GELU) v = 0.5f * v * (1.f + erff(v * 0.70710678118654752f));
          Cout[rowoff + col] = f2bf(v);
        }
      }
    }
  }
}

// ---------------- combine: out[t] = w0*Y[s0] + w1*Y[s1] ----------------
__global__ void combine_kernel(const unsigned short* __restrict__ Yb,
                               const int* __restrict__ slot_of,
                               const float* __restrict__ topk_w,
                               float* __restrict__ out) {
  int idx = blockIdx.x * 256 + threadIdx.x;  // T * (D/8) threads
  int t = idx >> 7;
  int d = (idx & 127) * 8;
  int s0 = slot_of[2 * t], s1 = slot_of[2 * t + 1];
  float w0 = topk_w[2 * t], w1 = topk_w[2 * t + 1];
  short8 y0 = *(const short8*)(Yb + (long)s0 * DIM + d);
  short8 y1 = *(const short8*)(Yb + (long)s1 * DIM + d);
  float o[8];
  #pragma unroll
  for (int j = 0; j < 8; j++)
    o[j] = w0 * bf2f((unsigned short)y0[j]) + w1 * bf2f((unsigned short)y1[j]);
  float4 lo = {o[0], o[1], o[2], o[3]};
  float4 hi = {o[4], o[5], o[6], o[7]};
  float* op = out + (long)t * DIM + d;
  *(float4*)op = lo;
  *(float4*)(op + 4) = hi;
}

extern "C" void kernel_launch(void* const* d_in, const int* in_sizes, int n_in,
                              void* d_out, int out_size, void* d_ws, size_t ws_size,
                              hipStream_t stream) {
  const float* x  = (const float*)d_in[0];   // [T, D]
  const float* Wr = (const float*)d_in[1];   // [D, E]
  const float* br = (const float*)d_in[2];   // [E]
  const float* W1 = (const float*)d_in[3];   // [E, D, H]
  const float* b1 = (const float*)d_in[4];   // [E, H]
  const float* W2 = (const float*)d_in[5];   // [E, H, D]
  const float* b2 = (const float*)d_in[6];   // [E, D]
  float* out = (float*)d_out;                // [T*D] ++ [1] aux

  char* ws = (char*)d_ws;
  // workspace layout (bytes)
  const long XB_OFF  = 0;                                   // T*D bf16      = 16 MB
  const long W1T_OFF = XB_OFF  + (long)T_TOKENS * DIM * 2;  // E*H*D bf16    = 33.5 MB ([E][H][D_k] -> [E][N][K])
  const long W2T_OFF = W1T_OFF + (long)NEXP * DIM * HDIM * 2;
  const long HB_OFF  = W2T_OFF + (long)NEXP * DIM * HDIM * 2; // NASSIGN*H bf16 = 67 MB
  const long YB_OFF  = HB_OFF  + (long)NASSIGN * HDIM * 2;    // NASSIGN*D bf16 = 33.5 MB
  const long META_OFF = YB_OFF + (long)NASSIGN * DIM * 2;

  unsigned short* Xb  = (unsigned short*)(ws + XB_OFF);
  unsigned short* W1T = (unsigned short*)(ws + W1T_OFF);
  unsigned short* W2T = (unsigned short*)(ws + W2T_OFF);
  unsigned short* Hb  = (unsigned short*)(ws + HB_OFF);
  unsigned short* Yb  = (unsigned short*)(ws + YB_OFF);

  char* meta = ws + META_OFF;
  int*   counts    = (int*)(meta + 0);
  int*   offsets   = (int*)(meta + 32);
  int*   fillc     = (int*)(meta + 64);
  float* probs_sum = (float*)(meta + 96);
  int*   topk_i    = (int*)(meta + 128);
  float* topk_w    = (float*)(meta + 128 + 65536);
  int*   token_list= (int*)(meta + 128 + 131072);
  int*   slot_of   = (int*)(meta + 128 + 196608);

  // zero counters (ws is poisoned 0xAA before every timed call)
  hipMemsetAsync(meta, 0, 128, stream);

  // 1. dtype conversions / layout transforms
  convert_x_kernel<<<(T_TOKENS * DIM / 4 + 255) / 256, 256, 0, stream>>>(
      x, Xb, (long)T_TOKENS * DIM);
  // W1: [E][K=1024][N=2048] -> [E][N][K]
  transpose_convert_kernel<<<dim3(HDIM / 32, DIM / 32, NEXP), dim3(32, 8), 0, stream>>>(
      W1, W1T, DIM, HDIM);
  // W2: [E][K=2048][N=1024] -> [E][N][K]
  transpose_convert_kernel<<<dim3(DIM / 32, HDIM / 32, NEXP), dim3(32, 8), 0, stream>>>(
      W2, W2T, HDIM, DIM);

  // 2. router (fp32)
  router_kernel<<<T_TOKENS / 4, 256, 0, stream>>>(x, Wr, br, topk_i, topk_w,
                                                  counts, probs_sum);
  // 3. scan + aux loss
  scan_aux_kernel<<<1, 64, 0, stream>>>(counts, offsets, probs_sum,
                                        out + (long)T_TOKENS * DIM);
  // 4. fill token lists
  fill_kernel<<<T_TOKENS / 256, 256, 0, stream>>>(topk_i, offsets, fillc,
                                                  token_list, slot_of);
  // 5. expert GEMM 1: H = gelu(X @ W1 + b1)   M=counts, N=2048, K=1024
  gemm_kernel<true, true><<<dim3(HDIM / 128, 64, NEXP), 256, 0, stream>>>(
      Xb, W1T, b1, Hb, counts, offsets, token_list, DIM, HDIM);
  // 6. expert GEMM 2: Y = H @ W2 + b2         M=counts, N=1024, K=2048
  gemm_kernel<false, false><<<dim3(DIM / 128, 64, NEXP), 256, 0, stream>>>(
      Hb, W2T, b2, Yb, counts, offsets, nullptr, HDIM, DIM);
  // 7. combine
  combine_kernel<<<T_TOKENS * (DIM / 8) / 256, 256, 0, stream>>>(
      Yb, slot_of, topk_w, out);
}

// Round 2
// 525.003 us; speedup vs baseline: 2.6370x; 2.6370x over previous
//
#include <hip/hip_runtime.h>
#include <math.h>

// Problem constants (B=4,S=2048,D=1024,H=2048,E=8, top-2)
#define T_TOKENS 8192
#define DIM      1024
#define HDIM     2048
#define NEXP     8
#define NASSIGN  16384   // T_TOKENS * 2
#define RBLOCKS  (T_TOKENS / 4)   // router blocks (4 tokens/block)

typedef __attribute__((ext_vector_type(8))) short short8;
typedef __attribute__((ext_vector_type(4))) float floatx4;

__device__ __forceinline__ unsigned short f2bf(float f) {
  unsigned u = __float_as_uint(f);
  u += 0x7fffu + ((u >> 16) & 1u);   // RNE
  return (unsigned short)(u >> 16);
}
__device__ __forceinline__ float bf2f(unsigned short h) {
  return __uint_as_float(((unsigned)h) << 16);
}

// ---------------- convert x fp32 -> bf16 ----------------
__global__ void convert_x_kernel(const float* __restrict__ in,
                                 unsigned short* __restrict__ out, long n) {
  long i = ((long)blockIdx.x * blockDim.x + threadIdx.x) * 4;
  if (i >= n) return;
  float4 v = *(const float4*)(in + i);
  ushort4 o;
  o.x = f2bf(v.x); o.y = f2bf(v.y); o.z = f2bf(v.z); o.w = f2bf(v.w);
  *(ushort4*)(out + i) = o;
}

// ------- transpose + convert: in [E][R][C] fp32 -> out [E][C][R] bf16 -------
__global__ void transpose_convert_kernel(const float* __restrict__ in,
                                         unsigned short* __restrict__ out,
                                         int R, int C) {
  __shared__ float tile[32][33];
  int e = blockIdx.z;
  int c0 = blockIdx.x * 32, r0 = blockIdx.y * 32;
  const float* inp = in + (long)e * R * C;
  unsigned short* outp = out + (long)e * R * C;
  int tx = threadIdx.x, ty = threadIdx.y;  // 32 x 8
  #pragma unroll
  for (int i = 0; i < 32; i += 8)
    tile[ty + i][tx] = inp[(long)(r0 + ty + i) * C + c0 + tx];
  __syncthreads();
  #pragma unroll
  for (int i = 0; i < 32; i += 8)
    outp[(long)(c0 + ty + i) * R + r0 + tx] = f2bf(tile[tx][ty + i]);
}

// ---------------- router: fp32, one wave per token, NO global atomics ------
__global__ __launch_bounds__(256) void router_kernel(
    const float* __restrict__ x, const float* __restrict__ Wr,
    const float* __restrict__ br,
    int* __restrict__ topk_i, float* __restrict__ topk_w,
    int* __restrict__ pc_partial,      // [RBLOCKS][NEXP]
    float* __restrict__ pp_partial) {  // [RBLOCKS][NEXP]
  __shared__ float sW[NEXP * DIM];  // transposed: sW[e*1024 + d], 32 KB
  __shared__ float sP[4][NEXP];
  __shared__ int   sC[4][NEXP];
  int tid = threadIdx.x;
  for (int i = tid; i < NEXP * DIM; i += 256) {
    int e = i >> 10, d = i & 1023;
    sW[i] = Wr[d * NEXP + e];
  }
  __syncthreads();
  int wid = tid >> 6, lane = tid & 63;
  int t = blockIdx.x * 4 + wid;
  const float* xp = x + (long)t * DIM;
  float acc[NEXP];
  #pragma unroll
  for (int e = 0; e < NEXP; e++) acc[e] = 0.f;
  #pragma unroll
  for (int i = 0; i < 16; i++) {
    float v = xp[i * 64 + lane];
    #pragma unroll
    for (int e = 0; e < NEXP; e++) acc[e] += v * sW[e * DIM + i * 64 + lane];
  }
  #pragma unroll
  for (int e = 0; e < NEXP; e++) {
    #pragma unroll
    for (int off = 32; off; off >>= 1) acc[e] += __shfl_xor(acc[e], off, 64);
  }
  if (lane == 0) {
    float l[NEXP];
    #pragma unroll
    for (int e = 0; e < NEXP; e++) l[e] = acc[e] + br[e];
    float mx = l[0];
    #pragma unroll
    for (int e = 1; e < NEXP; e++) mx = fmaxf(mx, l[e]);
    float p[NEXP], s = 0.f;
    #pragma unroll
    for (int e = 0; e < NEXP; e++) { p[e] = __expf(l[e] - mx); s += p[e]; }
    float inv = 1.f / s;
    #pragma unroll
    for (int e = 0; e < NEXP; e++) p[e] *= inv;
    // top-2, lowest index wins ties (matches lax.top_k)
    int i1 = 0;
    #pragma unroll
    for (int e = 1; e < NEXP; e++) if (l[e] > l[i1]) i1 = e;
    int i2 = (i1 == 0) ? 1 : 0;
    #pragma unroll
    for (int e = 0; e < NEXP; e++)
      if (e != i1 && l[e] > l[i2]) i2 = e;
    float s2 = p[i1] + p[i2];
    s2 = fmaxf(s2, 1e-9f);
    topk_i[2 * t] = i1; topk_i[2 * t + 1] = i2;
    topk_w[2 * t] = p[i1] / s2; topk_w[2 * t + 1] = p[i2] / s2;
    #pragma unroll
    for (int e = 0; e < NEXP; e++) {
      sP[wid][e] = p[e];
      sC[wid][e] = (e == i1 || e == i2) ? 1 : 0;
    }
  }
  __syncthreads();
  if (tid < NEXP) {
    float ps = 0.f; int cs = 0;
    #pragma unroll
    for (int w = 0; w < 4; w++) { ps += sP[w][tid]; cs += sC[w][tid]; }
    pp_partial[blockIdx.x * NEXP + tid] = ps;
    pc_partial[blockIdx.x * NEXP + tid] = cs;
  }
}

// ------- reduce partials -> counts/offsets, compute aux loss ----------
__global__ __launch_bounds__(256) void scan_aux_kernel(
    const int* __restrict__ pc_partial, const float* __restrict__ pp_partial,
    int* __restrict__ counts, int* __restrict__ offsets,
    float* __restrict__ aux_out) {
  __shared__ int sc[32][NEXP];
  __shared__ float sp[32][NEXP];
  int tid = threadIdx.x;
  int e = tid & 7, chunk = tid >> 3;  // 32 chunks of blocks
  int cs = 0; float ps = 0.f;
  for (int b = chunk; b < RBLOCKS; b += 32) {
    cs += pc_partial[b * NEXP + e];
    ps += pp_partial[b * NEXP + e];
  }
  sc[chunk][e] = cs; sp[chunk][e] = ps;
  __syncthreads();
  if (tid == 0) {
    int cnt[NEXP]; float prs[NEXP];
    #pragma unroll
    for (int ee = 0; ee < NEXP; ee++) { cnt[ee] = 0; prs[ee] = 0.f; }
    for (int c = 0; c < 32; c++)
      #pragma unroll
      for (int ee = 0; ee < NEXP; ee++) { cnt[ee] += sc[c][ee]; prs[ee] += sp[c][ee]; }
    int total = 0;
    #pragma unroll
    for (int ee = 0; ee < NEXP; ee++) total += cnt[ee];
    float inv_total = 1.f / (float)(total > 0 ? total : 1);
    int off = 0; float aux = 0.f;
    #pragma unroll
    for (int ee = 0; ee < NEXP; ee++) {
      counts[ee] = cnt[ee];
      offsets[ee] = off; off += cnt[ee];
      float importance = prs[ee] / (float)T_TOKENS;
      float load = (float)cnt[ee] * inv_total;
      aux += importance * load;
    }
    *aux_out = (float)NEXP * aux;
  }
}

// ---------------- fill per-expert token lists (ballot-batched atomics) -----
__global__ void fill_kernel(const int* __restrict__ topk_i,
                            const int* __restrict__ offsets,
                            int* __restrict__ fillc,
                            int* __restrict__ token_list,
                            int* __restrict__ slot_of) {
  int t = blockIdx.x * 256 + threadIdx.x;
  int lane = threadIdx.x & 63;
  #pragma unroll
  for (int k = 0; k < 2; k++) {
    int e = topk_i[2 * t + k];
    int slot = 0;
    #pragma unroll
    for (int eid = 0; eid < NEXP; eid++) {
      unsigned long long mask = __ballot(e == eid);
      if (e == eid) {
        int leader = __ffsll((unsigned long long)mask) - 1;
        int cnt = __popcll(mask);
        int base = 0;
        if (lane == leader) base = atomicAdd(&fillc[eid], cnt);
        base = __shfl(base, leader, 64);
        int pos = __popcll(mask & ((1ULL << lane) - 1ULL));
        slot = offsets[eid] + base + pos;
      }
    }
    token_list[slot] = t;
    slot_of[2 * t + k] = slot;
  }
}

// ---------------- grouped GEMM: 128x128 tile, bf16 MFMA ----------------
// C[r][n] = sum_k A[r][k] * B[k][n]  (+bias[n], optional exact-GELU)
// A rows gathered via token_list (GATHER) or direct (rowbase + r).
// BT is [E][N][K] (pre-transposed) so B-fragments are K-contiguous.
template<bool GELU, bool GATHER>
__global__ __launch_bounds__(256, 2) void gemm_kernel(
    const unsigned short* __restrict__ Abase,  // bf16 [*, K]
    const unsigned short* __restrict__ BT,     // bf16 [E][N][K]
    const float* __restrict__ bias,            // fp32 [E][N]
    unsigned short* __restrict__ Cout,         // bf16 [NASSIGN][N]
    const int* __restrict__ counts,
    const int* __restrict__ offsets,
    const int* __restrict__ token_list,
    int K, int N) {
  int e = blockIdx.z;
  int cnt = counts[e];
  int mtile = blockIdx.y;
  if (mtile * 128 >= cnt) return;
  int rowbase = offsets[e];
  int n0 = blockIdx.x * 128;
  int tid = threadIdx.x;

  __shared__ unsigned short As[128][72];
  __shared__ unsigned short Bs[128][72];

  // staging map: thread -> (row = tid>>1, k half = (tid&1)*32)
  int sr = tid >> 1;
  int sk = (tid & 1) * 32;
  int r_local = mtile * 128 + sr;
  long arow;
  if (GATHER) {
    int t = (r_local < cnt) ? token_list[rowbase + r_local] : 0;
    arow = (long)t * K;
  } else {
    int rr = rowbase + r_local;
    if (rr > NASSIGN - 1) rr = NASSIGN - 1;
    arow = (long)rr * K;
  }
  const unsigned short* Ap = Abase + arow + sk;
  const unsigned short* Bp = BT + ((long)e * N + (n0 + sr)) * K + sk;

  int wid = tid >> 6, lane = tid & 63;
  int wr = (wid >> 1) * 64, wc = (wid & 1) * 64;
  int lr = lane & 15, lq = lane >> 4;

  floatx4 zero = {0.f, 0.f, 0.f, 0.f};
  floatx4 acc[4][4];
  #pragma unroll
  for (int im = 0; im < 4; im++)
    #pragma unroll
    for (int in = 0; in < 4; in++) acc[im][in] = zero;

  for (int k0 = 0; k0 < K; k0 += 64) {
    const int4* ga = (const int4*)(Ap + k0);
    const int4* gb = (const int4*)(Bp + k0);
    int4 a0 = ga[0], a1 = ga[1], a2 = ga[2], a3 = ga[3];
    int4 b0 = gb[0], b1 = gb[1], b2 = gb[2], b3 = gb[3];
    *(int4*)&As[sr][sk + 0]  = a0;
    *(int4*)&As[sr][sk + 8]  = a1;
    *(int4*)&As[sr][sk + 16] = a2;
    *(int4*)&As[sr][sk + 24] = a3;
    *(int4*)&Bs[sr][sk + 0]  = b0;
    *(int4*)&Bs[sr][sk + 8]  = b1;
    *(int4*)&Bs[sr][sk + 16] = b2;
    *(int4*)&Bs[sr][sk + 24] = b3;
    __syncthreads();
    #pragma unroll
    for (int kk = 0; kk < 64; kk += 32) {
      short8 af[4], bf[4];
      #pragma unroll
      for (int im = 0; im < 4; im++)
        af[im] = *(const short8*)&As[wr + im * 16 + lr][kk + lq * 8];
      #pragma unroll
      for (int in = 0; in < 4; in++)
        bf[in] = *(const short8*)&Bs[wc + in * 16 + lr][kk + lq * 8];
      #pragma unroll
      for (int im = 0; im < 4; im++)
        #pragma unroll
        for (int in = 0; in < 4; in++)
          acc[im][in] = __builtin_amdgcn_mfma_f32_16x16x32_bf16(
              af[im], bf[in], acc[im][in], 0, 0, 0);
    }
    __syncthreads();
  }

  // epilogue: D[row=lq*4+j][col=lr] per fragment
  float bv[4];
  #pragma unroll
  for (int in = 0; in < 4; in++)
    bv[in] = bias[(long)e * N + n0 + wc + in * 16 + lr];
  #pragma unroll
  for (int im = 0; im < 4; im++) {
    int rbase = mtile * 128 + wr + im * 16 + lq * 4;
    #pragma unroll
    for (int j = 0; j < 4; j++) {
      int r = rbase + j;
      if (r < cnt) {
        long rowoff = (long)(rowbase + r) * N;
        #pragma unroll
        for (int in = 0; in < 4; in++) {
          int col = n0 + wc + in * 16 + lr;
          float v = acc[im][in][j] + bv[in];
          if (GELU) v = 0.5f * v * (1.f + erff(v * 0.70710678118654752f));
          Cout[rowoff + col] = f2bf(v);
        }
      }
    }
  }
}

// ---------------- combine: out[t] = w0*Y[s0] + w1*Y[s1] ----------------
__global__ void combine_kernel(const unsigned short* __restrict__ Yb,
                               const int* __restrict__ slot_of,
                               const float* __restrict__ topk_w,
                               float* __restrict__ out) {
  int idx = blockIdx.x * 256 + threadIdx.x;  // T * (D/8) threads
  int t = idx >> 7;
  int d = (idx & 127) * 8;
  int s0 = slot_of[2 * t], s1 = slot_of[2 * t + 1];
  float w0 = topk_w[2 * t], w1 = topk_w[2 * t + 1];
  short8 y0 = *(const short8*)(Yb + (long)s0 * DIM + d);
  short8 y1 = *(const short8*)(Yb + (long)s1 * DIM + d);
  float o[8];
  #pragma unroll
  for (int j = 0; j < 8; j++)
    o[j] = w0 * bf2f((unsigned short)y0[j]) + w1 * bf2f((unsigned short)y1[j]);
  float4 lo = {o[0], o[1], o[2], o[3]};
  float4 hi = {o[4], o[5], o[6], o[7]};
  float* op = out + (long)t * DIM + d;
  *(float4*)op = lo;
  *(float4*)(op + 4) = hi;
}

extern "C" void kernel_launch(void* const* d_in, const int* in_sizes, int n_in,
                              void* d_out, int out_size, void* d_ws, size_t ws_size,
                              hipStream_t stream) {
  const float* x  = (const float*)d_in[0];   // [T, D]
  const float* Wr = (const float*)d_in[1];   // [D, E]
  const float* br = (const float*)d_in[2];   // [E]
  const float* W1 = (const float*)d_in[3];   // [E, D, H]
  const float* b1 = (const float*)d_in[4];   // [E, H]
  const float* W2 = (const float*)d_in[5];   // [E, H, D]
  const float* b2 = (const float*)d_in[6];   // [E, D]
  float* out = (float*)d_out;                // [T*D] ++ [1] aux

  char* ws = (char*)d_ws;
  // workspace layout (bytes)
  const long XB_OFF  = 0;                                   // T*D bf16      = 16 MB
  const long W1T_OFF = XB_OFF  + (long)T_TOKENS * DIM * 2;  // E*H*D bf16
  const long W2T_OFF = W1T_OFF + (long)NEXP * DIM * HDIM * 2;
  const long HB_OFF  = W2T_OFF + (long)NEXP * DIM * HDIM * 2; // NASSIGN*H bf16
  const long YB_OFF  = HB_OFF  + (long)NASSIGN * HDIM * 2;    // NASSIGN*D bf16
  const long META_OFF = YB_OFF + (long)NASSIGN * DIM * 2;

  unsigned short* Xb  = (unsigned short*)(ws + XB_OFF);
  unsigned short* W1T = (unsigned short*)(ws + W1T_OFF);
  unsigned short* W2T = (unsigned short*)(ws + W2T_OFF);
  unsigned short* Hb  = (unsigned short*)(ws + HB_OFF);
  unsigned short* Yb  = (unsigned short*)(ws + YB_OFF);

  char* meta = ws + META_OFF;
  int*   counts    = (int*)(meta + 0);
  int*   offsets   = (int*)(meta + 32);
  int*   fillc     = (int*)(meta + 64);
  int*   topk_i    = (int*)(meta + 128);
  float* topk_w    = (float*)(meta + 128 + 65536);
  int*   token_list= (int*)(meta + 128 + 131072);
  int*   slot_of   = (int*)(meta + 128 + 196608);
  int*   pc_part   = (int*)(meta + 128 + 262144);           // [RBLOCKS][8]
  float* pp_part   = (float*)(meta + 128 + 262144 + 65536); // [RBLOCKS][8]

  // zero counters (ws is poisoned 0xAA before every timed call)
  hipMemsetAsync(meta, 0, 128, stream);

  // 1. dtype conversions / layout transforms
  convert_x_kernel<<<(T_TOKENS * DIM / 4 + 255) / 256, 256, 0, stream>>>(
      x, Xb, (long)T_TOKENS * DIM);
  // W1: [E][K=1024][N=2048] -> [E][N][K]
  transpose_convert_kernel<<<dim3(HDIM / 32, DIM / 32, NEXP), dim3(32, 8), 0, stream>>>(
      W1, W1T, DIM, HDIM);
  // W2: [E][K=2048][N=1024] -> [E][N][K]
  transpose_convert_kernel<<<dim3(DIM / 32, HDIM / 32, NEXP), dim3(32, 8), 0, stream>>>(
      W2, W2T, HDIM, DIM);

  // 2. router (fp32, atomic-free)
  router_kernel<<<RBLOCKS, 256, 0, stream>>>(x, Wr, br, topk_i, topk_w,
                                             pc_part, pp_part);
  // 3. reduce partials + offsets + aux loss
  scan_aux_kernel<<<1, 256, 0, stream>>>(pc_part, pp_part, counts, offsets,
                                         out + (long)T_TOKENS * DIM);
  // 4. fill token lists
  fill_kernel<<<T_TOKENS / 256, 256, 0, stream>>>(topk_i, offsets, fillc,
                                                  token_list, slot_of);
  // 5. expert GEMM 1: H = gelu(X @ W1 + b1)   M=counts, N=2048, K=1024
  gemm_kernel<true, true><<<dim3(HDIM / 128, 64, NEXP), 256, 0, stream>>>(
      Xb, W1T, b1, Hb, counts, offsets, token_list, DIM, HDIM);
  // 6. expert GEMM 2: Y = H @ W2 + b2         M=counts, N=1024, K=2048
  gemm_kernel<false, false><<<dim3(DIM / 128, 64, NEXP), 256, 0, stream>>>(
      Hb, W2T, b2, Yb, counts, offsets, nullptr, HDIM, DIM);
  // 7. combine
  combine_kernel<<<T_TOKENS * (DIM / 8) / 256, 256, 0, stream>>>(
      Yb, slot_of, topk_w, out);
}

// Round 3
// 463.183 us; speedup vs baseline: 2.9890x; 1.1335x over previous
//
#include <hip/hip_runtime.h>
#include <math.h>

// Problem constants (B=4,S=2048,D=1024,H=2048,E=8, top-2)
#define T_TOKENS 8192
#define DIM      1024
#define HDIM     2048
#define NEXP     8
#define NASSIGN  16384   // T_TOKENS * 2
#define RBLOCKS  (T_TOKENS / 4)   // router blocks (4 tokens/block)
#define BK       64      // GEMM K-tile

typedef __attribute__((ext_vector_type(8))) short short8;
typedef __attribute__((ext_vector_type(4))) float floatx4;
typedef __attribute__((address_space(3))) void lds_void;
typedef const __attribute__((address_space(1))) void gbl_void;

__device__ __forceinline__ unsigned short f2bf(float f) {
  unsigned u = __float_as_uint(f);
  u += 0x7fffu + ((u >> 16) & 1u);   // RNE
  return (unsigned short)(u >> 16);
}
__device__ __forceinline__ float bf2f(unsigned short h) {
  return __uint_as_float(((unsigned)h) << 16);
}

// ------- transpose + convert: in [E][R][C] fp32 -> out [E][C][R] bf16 -------
__global__ void transpose_convert_kernel(const float* __restrict__ in,
                                         unsigned short* __restrict__ out,
                                         int R, int C) {
  __shared__ float tile[32][33];
  int e = blockIdx.z;
  int c0 = blockIdx.x * 32, r0 = blockIdx.y * 32;
  const float* inp = in + (long)e * R * C;
  unsigned short* outp = out + (long)e * R * C;
  int tx = threadIdx.x, ty = threadIdx.y;  // 32 x 8
  #pragma unroll
  for (int i = 0; i < 32; i += 8)
    tile[ty + i][tx] = inp[(long)(r0 + ty + i) * C + c0 + tx];
  __syncthreads();
  #pragma unroll
  for (int i = 0; i < 32; i += 8)
    outp[(long)(c0 + ty + i) * R + r0 + tx] = f2bf(tile[tx][ty + i]);
}

// ------- router: fp32 logits, fused x->bf16 convert, no global atomics -----
__global__ __launch_bounds__(256) void router_kernel(
    const float* __restrict__ x, const float* __restrict__ Wr,
    const float* __restrict__ br, unsigned short* __restrict__ Xb,
    int* __restrict__ topk_i, float* __restrict__ topk_w,
    int* __restrict__ pc_partial,      // [RBLOCKS][NEXP]
    float* __restrict__ pp_partial) {  // [RBLOCKS][NEXP]
  __shared__ float sW[NEXP * DIM];  // transposed: sW[e*1024 + d], 32 KB
  __shared__ float sP[4][NEXP];
  __shared__ int   sC[4][NEXP];
  int tid = threadIdx.x;
  for (int i = tid; i < NEXP * DIM; i += 256) {
    int e = i >> 10, d = i & 1023;
    sW[i] = Wr[d * NEXP + e];
  }
  __syncthreads();
  int wid = tid >> 6, lane = tid & 63;
  int t = blockIdx.x * 4 + wid;
  const float* xp = x + (long)t * DIM;
  unsigned short* xbp = Xb + (long)t * DIM;
  float acc[NEXP];
  #pragma unroll
  for (int e = 0; e < NEXP; e++) acc[e] = 0.f;
  #pragma unroll
  for (int i = 0; i < 4; i++) {
    int off = i * 256 + lane * 4;
    float4 v = *(const float4*)(xp + off);
    ushort4 o;
    o.x = f2bf(v.x); o.y = f2bf(v.y); o.z = f2bf(v.z); o.w = f2bf(v.w);
    *(ushort4*)(xbp + off) = o;
    #pragma unroll
    for (int e = 0; e < NEXP; e++) {
      float4 w = *(const float4*)&sW[e * DIM + off];
      acc[e] += v.x * w.x + v.y * w.y + v.z * w.z + v.w * w.w;
    }
  }
  #pragma unroll
  for (int e = 0; e < NEXP; e++) {
    #pragma unroll
    for (int off = 32; off; off >>= 1) acc[e] += __shfl_xor(acc[e], off, 64);
  }
  if (lane == 0) {
    float l[NEXP];
    #pragma unroll
    for (int e = 0; e < NEXP; e++) l[e] = acc[e] + br[e];
    float mx = l[0];
    #pragma unroll
    for (int e = 1; e < NEXP; e++) mx = fmaxf(mx, l[e]);
    float p[NEXP], s = 0.f;
    #pragma unroll
    for (int e = 0; e < NEXP; e++) { p[e] = __expf(l[e] - mx); s += p[e]; }
    float inv = 1.f / s;
    #pragma unroll
    for (int e = 0; e < NEXP; e++) p[e] *= inv;
    // top-2, lowest index wins ties (matches lax.top_k)
    int i1 = 0;
    #pragma unroll
    for (int e = 1; e < NEXP; e++) if (l[e] > l[i1]) i1 = e;
    int i2 = (i1 == 0) ? 1 : 0;
    #pragma unroll
    for (int e = 0; e < NEXP; e++)
      if (e != i1 && l[e] > l[i2]) i2 = e;
    float s2 = p[i1] + p[i2];
    s2 = fmaxf(s2, 1e-9f);
    topk_i[2 * t] = i1; topk_i[2 * t + 1] = i2;
    topk_w[2 * t] = p[i1] / s2; topk_w[2 * t + 1] = p[i2] / s2;
    #pragma unroll
    for (int e = 0; e < NEXP; e++) {
      sP[wid][e] = p[e];
      sC[wid][e] = (e == i1 || e == i2) ? 1 : 0;
    }
  }
  __syncthreads();
  if (tid < NEXP) {
    float ps = 0.f; int cs = 0;
    #pragma unroll
    for (int w = 0; w < 4; w++) { ps += sP[w][tid]; cs += sC[w][tid]; }
    pp_partial[blockIdx.x * NEXP + tid] = ps;
    pc_partial[blockIdx.x * NEXP + tid] = cs;
  }
}

// ------- reduce partials -> counts/offsets, compute aux loss ----------
__global__ __launch_bounds__(256) void scan_aux_kernel(
    const int* __restrict__ pc_partial, const float* __restrict__ pp_partial,
    int* __restrict__ counts, int* __restrict__ offsets,
    float* __restrict__ aux_out) {
  __shared__ int sc[32][NEXP];
  __shared__ float sp[32][NEXP];
  int tid = threadIdx.x;
  int e = tid & 7, chunk = tid >> 3;  // 32 chunks of blocks
  int cs = 0; float ps = 0.f;
  for (int b = chunk; b < RBLOCKS; b += 32) {
    cs += pc_partial[b * NEXP + e];
    ps += pp_partial[b * NEXP + e];
  }
  sc[chunk][e] = cs; sp[chunk][e] = ps;
  __syncthreads();
  if (tid == 0) {
    int cnt[NEXP]; float prs[NEXP];
    #pragma unroll
    for (int ee = 0; ee < NEXP; ee++) { cnt[ee] = 0; prs[ee] = 0.f; }
    for (int c = 0; c < 32; c++)
      #pragma unroll
      for (int ee = 0; ee < NEXP; ee++) { cnt[ee] += sc[c][ee]; prs[ee] += sp[c][ee]; }
    int total = 0;
    #pragma unroll
    for (int ee = 0; ee < NEXP; ee++) total += cnt[ee];
    float inv_total = 1.f / (float)(total > 0 ? total : 1);
    int off = 0; float aux = 0.f;
    #pragma unroll
    for (int ee = 0; ee < NEXP; ee++) {
      counts[ee] = cnt[ee];
      offsets[ee] = off; off += cnt[ee];
      float importance = prs[ee] / (float)T_TOKENS;
      float load = (float)cnt[ee] * inv_total;
      aux += importance * load;
    }
    *aux_out = (float)NEXP * aux;
  }
}

// ---------------- fill per-expert token lists (ballot-batched atomics) -----
__global__ void fill_kernel(const int* __restrict__ topk_i,
                            const int* __restrict__ offsets,
                            int* __restrict__ fillc,
                            int* __restrict__ token_list,
                            int* __restrict__ slot_of) {
  int t = blockIdx.x * 256 + threadIdx.x;
  int lane = threadIdx.x & 63;
  #pragma unroll
  for (int k = 0; k < 2; k++) {
    int e = topk_i[2 * t + k];
    int slot = 0;
    #pragma unroll
    for (int eid = 0; eid < NEXP; eid++) {
      unsigned long long mask = __ballot(e == eid);
      if (e == eid) {
        int leader = __ffsll((unsigned long long)mask) - 1;
        int cnt = __popcll(mask);
        int base = 0;
        if (lane == leader) base = atomicAdd(&fillc[eid], cnt);
        base = __shfl(base, leader, 64);
        int pos = __popcll(mask & ((1ULL << lane) - 1ULL));
        slot = offsets[eid] + base + pos;
      }
    }
    token_list[slot] = t;
    slot_of[2 * t + k] = slot;
  }
}

// ---------------- grouped GEMM: 128x128 tile, async LDS staging -----------
// xcd = expert swizzle: blockIdx round-robins over 8 XCDs; xcd e keeps its
// expert's whole B (4 MB) resident in its private L2.
// LDS tiles are unpadded [128][64]; global source is XOR-swizzled per lane
// (chunk p holds logical chunk p^(row&7)) so ds_read_b128 frag reads are
// bank-uniform. global_load_lds scatters lane i -> base + 16*i (m97/m104).
template<bool GELU, bool GATHER, int NXN>
__global__ __launch_bounds__(256, 2) void gemm_kernel(
    const unsigned short* __restrict__ Abase,  // bf16 [*, K]
    const unsigned short* __restrict__ BT,     // bf16 [E][N][K]
    const float* __restrict__ bias,            // fp32 [E][N]
    unsigned short* __restrict__ Cout,         // bf16 [NASSIGN][N]
    const int* __restrict__ counts,
    const int* __restrict__ offsets,
    const int* __restrict__ token_list,
    int K, int N) {
  int flat = blockIdx.x;
  int e = flat & 7;          // xcd-local expert
  int q = flat >> 3;
  int n_idx = q % NXN;
  int mtile = q / NXN;
  int cnt = counts[e];
  if (mtile * 128 >= cnt) return;
  int rowbase = offsets[e];
  int n0 = n_idx * 128;
  int tid = threadIdx.x;
  int wid = tid >> 6, lane = tid & 63;

  __shared__ unsigned short As[128 * BK];
  __shared__ unsigned short Bs[128 * BK];

  // staging: wave w stages rows [32w, 32w+32), 4 instrs x (8 rows x 8 chunks)
  const unsigned short* asrc[4];
  const unsigned short* bsrc[4];
  #pragma unroll
  for (int j = 0; j < 4; j++) {
    int r = wid * 32 + j * 8 + (lane >> 3);  // tile row 0..127
    int p = lane & 7;                        // 16B chunk in lane-linear dest
    int swz = ((p ^ (r & 7)) * 8);           // source element offset in row
    long arow;
    if (GATHER) {
      int rl = mtile * 128 + r;
      int t = token_list[rowbase + min(rl, cnt - 1)];
      arow = (long)t * K;
    } else {
      int rr = rowbase + min(mtile * 128 + r, cnt - 1);
      arow = (long)rr * K;
    }
    asrc[j] = Abase + arow + swz;
    bsrc[j] = BT + ((long)e * N + n0 + r) * K + swz;
  }

  int wr = (wid >> 1) * 64, wc = (wid & 1) * 64;
  int lr = lane & 15, lq = lane >> 4;

  floatx4 zero = {0.f, 0.f, 0.f, 0.f};
  floatx4 acc[4][4];
  #pragma unroll
  for (int im = 0; im < 4; im++)
    #pragma unroll
    for (int in = 0; in < 4; in++) acc[im][in] = zero;

  for (int k0 = 0; k0 < K; k0 += BK) {
    #pragma unroll
    for (int j = 0; j < 4; j++) {
      int dst = (wid * 32 + j * 8) * BK;  // element offset of instr dest
      __builtin_amdgcn_global_load_lds((gbl_void*)(asrc[j] + k0),
                                       (lds_void*)&As[dst], 16, 0, 0);
      __builtin_amdgcn_global_load_lds((gbl_void*)(bsrc[j] + k0),
                                       (lds_void*)&Bs[dst], 16, 0, 0);
    }
    __syncthreads();
    #pragma unroll
    for (int kk = 0; kk < 2; kk++) {
      short8 af[4], bf[4];
      #pragma unroll
      for (int im = 0; im < 4; im++) {
        int r = wr + im * 16 + lr;
        int c = kk * 4 + lq;
        af[im] = *(const short8*)&As[r * BK + ((c ^ (r & 7)) * 8)];
      }
      #pragma unroll
      for (int in = 0; in < 4; in++) {
        int r = wc + in * 16 + lr;
        int c = kk * 4 + lq;
        bf[in] = *(const short8*)&Bs[r * BK + ((c ^ (r & 7)) * 8)];
      }
      #pragma unroll
      for (int im = 0; im < 4; im++)
        #pragma unroll
        for (int in = 0; in < 4; in++)
          acc[im][in] = __builtin_amdgcn_mfma_f32_16x16x32_bf16(
              af[im], bf[in], acc[im][in], 0, 0, 0);
    }
    __syncthreads();
  }

  // epilogue: D[row=lq*4+j][col=lr] per fragment
  float bv[4];
  #pragma unroll
  for (int in = 0; in < 4; in++)
    bv[in] = bias[(long)e * N + n0 + wc + in * 16 + lr];
  #pragma unroll
  for (int im = 0; im < 4; im++) {
    int rbase = mtile * 128 + wr + im * 16 + lq * 4;
    #pragma unroll
    for (int j = 0; j < 4; j++) {
      int r = rbase + j;
      if (r < cnt) {
        long rowoff = (long)(rowbase + r) * N;
        #pragma unroll
        for (int in = 0; in < 4; in++) {
          int col = n0 + wc + in * 16 + lr;
          float v = acc[im][in][j] + bv[in];
          if (GELU) v = 0.5f * v * (1.f + erff(v * 0.70710678118654752f));
          Cout[rowoff + col] = f2bf(v);
        }
      }
    }
  }
}

// ---------------- combine: out[t] = w0*Y[s0] + w1*Y[s1] ----------------
__global__ void combine_kernel(const unsigned short* __restrict__ Yb,
                               const int* __restrict__ slot_of,
                               const float* __restrict__ topk_w,
                               float* __restrict__ out) {
  int idx = blockIdx.x * 256 + threadIdx.x;  // T * (D/8) threads
  int t = idx >> 7;
  int d = (idx & 127) * 8;
  int s0 = slot_of[2 * t], s1 = slot_of[2 * t + 1];
  float w0 = topk_w[2 * t], w1 = topk_w[2 * t + 1];
  short8 y0 = *(const short8*)(Yb + (long)s0 * DIM + d);
  short8 y1 = *(const short8*)(Yb + (long)s1 * DIM + d);
  float o[8];
  #pragma unroll
  for (int j = 0; j < 8; j++)
    o[j] = w0 * bf2f((unsigned short)y0[j]) + w1 * bf2f((unsigned short)y1[j]);
  float4 lo = {o[0], o[1], o[2], o[3]};
  float4 hi = {o[4], o[5], o[6], o[7]};
  float* op = out + (long)t * DIM + d;
  *(float4*)op = lo;
  *(float4*)(op + 4) = hi;
}

extern "C" void kernel_launch(void* const* d_in, const int* in_sizes, int n_in,
                              void* d_out, int out_size, void* d_ws, size_t ws_size,
                              hipStream_t stream) {
  const float* x  = (const float*)d_in[0];   // [T, D]
  const float* Wr = (const float*)d_in[1];   // [D, E]
  const float* br = (const float*)d_in[2];   // [E]
  const float* W1 = (const float*)d_in[3];   // [E, D, H]
  const float* b1 = (const float*)d_in[4];   // [E, H]
  const float* W2 = (const float*)d_in[5];   // [E, H, D]
  const float* b2 = (const float*)d_in[6];   // [E, D]
  float* out = (float*)d_out;                // [T*D] ++ [1] aux

  char* ws = (char*)d_ws;
  // workspace layout (bytes)
  const long XB_OFF  = 0;                                   // T*D bf16
  const long W1T_OFF = XB_OFF  + (long)T_TOKENS * DIM * 2;  // E*H*D bf16
  const long W2T_OFF = W1T_OFF + (long)NEXP * DIM * HDIM * 2;
  const long HB_OFF  = W2T_OFF + (long)NEXP * DIM * HDIM * 2; // NASSIGN*H bf16
  const long YB_OFF  = HB_OFF  + (long)NASSIGN * HDIM * 2;    // NASSIGN*D bf16
  const long META_OFF = YB_OFF + (long)NASSIGN * DIM * 2;

  unsigned short* Xb  = (unsigned short*)(ws + XB_OFF);
  unsigned short* W1T = (unsigned short*)(ws + W1T_OFF);
  unsigned short* W2T = (unsigned short*)(ws + W2T_OFF);
  unsigned short* Hb  = (unsigned short*)(ws + HB_OFF);
  unsigned short* Yb  = (unsigned short*)(ws + YB_OFF);

  char* meta = ws + META_OFF;
  int*   counts    = (int*)(meta + 0);
  int*   offsets   = (int*)(meta + 32);
  int*   fillc     = (int*)(meta + 64);
  int*   topk_i    = (int*)(meta + 128);
  float* topk_w    = (float*)(meta + 128 + 65536);
  int*   token_list= (int*)(meta + 128 + 131072);
  int*   slot_of   = (int*)(meta + 128 + 196608);
  int*   pc_part   = (int*)(meta + 128 + 262144);           // [RBLOCKS][8]
  float* pp_part   = (float*)(meta + 128 + 262144 + 65536); // [RBLOCKS][8]

  // zero counters (ws is poisoned 0xAA before every timed call)
  hipMemsetAsync(meta, 0, 128, stream);

  // 1. weight layout transforms
  // W1: [E][K=1024][N=2048] -> [E][N][K]
  transpose_convert_kernel<<<dim3(HDIM / 32, DIM / 32, NEXP), dim3(32, 8), 0, stream>>>(
      W1, W1T, DIM, HDIM);
  // W2: [E][K=2048][N=1024] -> [E][N][K]
  transpose_convert_kernel<<<dim3(DIM / 32, HDIM / 32, NEXP), dim3(32, 8), 0, stream>>>(
      W2, W2T, HDIM, DIM);

  // 2. router (fp32, atomic-free, fused x->bf16)
  router_kernel<<<RBLOCKS, 256, 0, stream>>>(x, Wr, br, Xb, topk_i, topk_w,
                                             pc_part, pp_part);
  // 3. reduce partials + offsets + aux loss
  scan_aux_kernel<<<1, 256, 0, stream>>>(pc_part, pp_part, counts, offsets,
                                         out + (long)T_TOKENS * DIM);
  // 4. fill token lists
  fill_kernel<<<T_TOKENS / 256, 256, 0, stream>>>(topk_i, offsets, fillc,
                                                  token_list, slot_of);
  // 5. expert GEMM 1: H = gelu(X @ W1 + b1)   M=counts, N=2048, K=1024
  gemm_kernel<true, true, HDIM / 128><<<NEXP * 64 * (HDIM / 128), 256, 0, stream>>>(
      Xb, W1T, b1, Hb, counts, offsets, token_list, DIM, HDIM);
  // 6. expert GEMM 2: Y = H @ W2 + b2         M=counts, N=1024, K=2048
  gemm_kernel<false, false, DIM / 128><<<NEXP * 64 * (DIM / 128), 256, 0, stream>>>(
      Hb, W2T, b2, Yb, counts, offsets, nullptr, HDIM, DIM);
  // 7. combine
  combine_kernel<<<T_TOKENS * (DIM / 8) / 256, 256, 0, stream>>>(
      Yb, slot_of, topk_w, out);
}

// Round 4
// 452.828 us; speedup vs baseline: 3.0573x; 1.0229x over previous
//
#include <hip/hip_runtime.h>
#include <math.h>

// Problem constants (B=4,S=2048,D=1024,H=2048,E=8, top-2)
#define T_TOKENS 8192
#define DIM      1024
#define HDIM     2048
#define NEXP     8
#define NASSIGN  16384   // T_TOKENS * 2
#define RTOK     16      // tokens per router block
#define RBLOCKS  (T_TOKENS / RTOK)
#define BK       64      // GEMM K-tile

typedef __attribute__((ext_vector_type(8))) short short8;
typedef __attribute__((ext_vector_type(16))) float floatx16;
typedef __attribute__((address_space(3))) void lds_void;
typedef const __attribute__((address_space(1))) void gbl_void;

__device__ __forceinline__ unsigned short f2bf(float f) {
  unsigned u = __float_as_uint(f);
  u += 0x7fffu + ((u >> 16) & 1u);   // RNE
  return (unsigned short)(u >> 16);
}
__device__ __forceinline__ float bf2f(unsigned short h) {
  return __uint_as_float(((unsigned)h) << 16);
}

// fast GELU: v * sigmoid(1.5958*(v + 0.044715 v^3)); max abs err ~1e-3 vs erf
__device__ __forceinline__ float gelu_fast(float v) {
  float u = 1.5957691216057308f * v * fmaf(0.044715f * v, v, 1.0f);
  return v / (1.f + __expf(-u));
}

// ------- fused transpose+convert: W1 and W2, [E][R][C] fp32 -> [E][C][R] bf16
__global__ __launch_bounds__(256) void transpose_convert2_kernel(
    const float* __restrict__ W1, const float* __restrict__ W2,
    unsigned short* __restrict__ W1T, unsigned short* __restrict__ W2T) {
  __shared__ float tile[64][65];
  int b = blockIdx.x;
  const float* inp; unsigned short* outp; int R, C, r0, c0;
  if (b < 4096) {                       // W1: R=1024, C=2048; 512 tiles/expert
    int e = b >> 9, t = b & 511;
    R = DIM; C = HDIM;
    c0 = (t & 31) * 64; r0 = (t >> 5) * 64;
    long eb = (long)e * R * C;
    inp = W1 + eb; outp = W1T + eb;
  } else {                              // W2: R=2048, C=1024
    int bb = b - 4096;
    int e = bb >> 9, t = bb & 511;
    R = HDIM; C = DIM;
    c0 = (t & 15) * 64; r0 = (t >> 4) * 64;
    long eb = (long)e * R * C;
    inp = W2 + eb; outp = W2T + eb;
  }
  int tid = threadIdx.x;
  int rr = tid >> 4, c4 = (tid & 15) * 4;
  #pragma unroll
  for (int i = 0; i < 4; i++) {
    float4 v = *(const float4*)(inp + (long)(r0 + rr + i * 16) * C + c0 + c4);
    tile[rr + i * 16][c4 + 0] = v.x;
    tile[rr + i * 16][c4 + 1] = v.y;
    tile[rr + i * 16][c4 + 2] = v.z;
    tile[rr + i * 16][c4 + 3] = v.w;
  }
  __syncthreads();
  int rq = (tid & 15) * 4, cc = tid >> 4;
  #pragma unroll
  for (int i = 0; i < 4; i++) {
    int c = cc + i * 16;
    ushort4 o;
    o.x = f2bf(tile[rq + 0][c]);
    o.y = f2bf(tile[rq + 1][c]);
    o.z = f2bf(tile[rq + 2][c]);
    o.w = f2bf(tile[rq + 3][c]);
    *(ushort4*)(outp + (long)(c0 + c) * R + r0 + rq) = o;
  }
}

// ------- router: fp32 logits, fused x->bf16 convert, no global atomics -----
__global__ __launch_bounds__(256) void router_kernel(
    const float* __restrict__ x, const float* __restrict__ Wr,
    const float* __restrict__ br, unsigned short* __restrict__ Xb,
    int* __restrict__ topk_i, float* __restrict__ topk_w,
    int* __restrict__ pc_partial,      // [RBLOCKS][NEXP]
    float* __restrict__ pp_partial) {  // [RBLOCKS][NEXP]
  __shared__ float sW[NEXP * DIM];  // transposed: sW[e*1024 + d], 32 KB
  __shared__ float sP[4][NEXP];
  __shared__ int   sC[4][NEXP];
  int tid = threadIdx.x;
  for (int i = tid; i < NEXP * DIM; i += 256)   // coalesced load, scatter store
    sW[(i & 7) * DIM + (i >> 3)] = Wr[i];
  __syncthreads();
  int wid = tid >> 6, lane = tid & 63;
  float pacc[NEXP]; int cacc[NEXP];
  #pragma unroll
  for (int e = 0; e < NEXP; e++) { pacc[e] = 0.f; cacc[e] = 0; }
  #pragma unroll
  for (int it = 0; it < 4; it++) {
    int t = blockIdx.x * RTOK + wid * 4 + it;
    const float* xp = x + (long)t * DIM;
    unsigned short* xbp = Xb + (long)t * DIM;
    float acc[NEXP];
    #pragma unroll
    for (int e = 0; e < NEXP; e++) acc[e] = 0.f;
    #pragma unroll
    for (int i = 0; i < 4; i++) {
      int off = i * 256 + lane * 4;
      float4 v = *(const float4*)(xp + off);
      ushort4 o;
      o.x = f2bf(v.x); o.y = f2bf(v.y); o.z = f2bf(v.z); o.w = f2bf(v.w);
      *(ushort4*)(xbp + off) = o;
      #pragma unroll
      for (int e = 0; e < NEXP; e++) {
        float4 w = *(const float4*)&sW[e * DIM + off];
        acc[e] += v.x * w.x + v.y * w.y + v.z * w.z + v.w * w.w;
      }
    }
    #pragma unroll
    for (int e = 0; e < NEXP; e++) {
      #pragma unroll
      for (int off = 32; off; off >>= 1) acc[e] += __shfl_xor(acc[e], off, 64);
    }
    if (lane == 0) {
      float l[NEXP];
      #pragma unroll
      for (int e = 0; e < NEXP; e++) l[e] = acc[e] + br[e];
      float mx = l[0];
      #pragma unroll
      for (int e = 1; e < NEXP; e++) mx = fmaxf(mx, l[e]);
      float p[NEXP], s = 0.f;
      #pragma unroll
      for (int e = 0; e < NEXP; e++) { p[e] = __expf(l[e] - mx); s += p[e]; }
      float inv = 1.f / s;
      #pragma unroll
      for (int e = 0; e < NEXP; e++) p[e] *= inv;
      // top-2, lowest index wins ties (matches lax.top_k)
      int i1 = 0;
      #pragma unroll
      for (int e = 1; e < NEXP; e++) if (l[e] > l[i1]) i1 = e;
      int i2 = (i1 == 0) ? 1 : 0;
      #pragma unroll
      for (int e = 0; e < NEXP; e++)
        if (e != i1 && l[e] > l[i2]) i2 = e;
      float s2 = fmaxf(p[i1] + p[i2], 1e-9f);
      topk_i[2 * t] = i1; topk_i[2 * t + 1] = i2;
      topk_w[2 * t] = p[i1] / s2; topk_w[2 * t + 1] = p[i2] / s2;
      #pragma unroll
      for (int e = 0; e < NEXP; e++) {
        pacc[e] += p[e];
        cacc[e] += (e == i1 || e == i2) ? 1 : 0;
      }
    }
  }
  if (lane == 0) {
    #pragma unroll
    for (int e = 0; e < NEXP; e++) { sP[wid][e] = pacc[e]; sC[wid][e] = cacc[e]; }
  }
  __syncthreads();
  if (tid < NEXP) {
    float ps = 0.f; int cs = 0;
    #pragma unroll
    for (int w = 0; w < 4; w++) { ps += sP[w][tid]; cs += sC[w][tid]; }
    pp_partial[blockIdx.x * NEXP + tid] = ps;
    pc_partial[blockIdx.x * NEXP + tid] = cs;
  }
}

// ------- reduce partials -> counts/offsets, compute aux loss ----------
__global__ __launch_bounds__(256) void scan_aux_kernel(
    const int* __restrict__ pc_partial, const float* __restrict__ pp_partial,
    int* __restrict__ counts, int* __restrict__ offsets,
    float* __restrict__ aux_out) {
  __shared__ int sc[32][NEXP];
  __shared__ float sp[32][NEXP];
  int tid = threadIdx.x;
  int e = tid & 7, chunk = tid >> 3;  // 32 chunks of blocks
  int cs = 0; float ps = 0.f;
  for (int b = chunk; b < RBLOCKS; b += 32) {
    cs += pc_partial[b * NEXP + e];
    ps += pp_partial[b * NEXP + e];
  }
  sc[chunk][e] = cs; sp[chunk][e] = ps;
  __syncthreads();
  if (tid == 0) {
    int cnt[NEXP]; float prs[NEXP];
    #pragma unroll
    for (int ee = 0; ee < NEXP; ee++) { cnt[ee] = 0; prs[ee] = 0.f; }
    for (int c = 0; c < 32; c++)
      #pragma unroll
      for (int ee = 0; ee < NEXP; ee++) { cnt[ee] += sc[c][ee]; prs[ee] += sp[c][ee]; }
    int total = 0;
    #pragma unroll
    for (int ee = 0; ee < NEXP; ee++) total += cnt[ee];
    float inv_total = 1.f / (float)(total > 0 ? total : 1);
    int off = 0; float aux = 0.f;
    #pragma unroll
    for (int ee = 0; ee < NEXP; ee++) {
      counts[ee] = cnt[ee];
      offsets[ee] = off; off += cnt[ee];
      float importance = prs[ee] / (float)T_TOKENS;
      float load = (float)cnt[ee] * inv_total;
      aux += importance * load;
    }
    *aux_out = (float)NEXP * aux;
  }
}

// ---------------- fill per-expert token lists (ballot-batched atomics) -----
__global__ void fill_kernel(const int* __restrict__ topk_i,
                            const int* __restrict__ offsets,
                            int* __restrict__ fillc,
                            int* __restrict__ token_list,
                            int* __restrict__ slot_of) {
  int t = blockIdx.x * 256 + threadIdx.x;
  int lane = threadIdx.x & 63;
  #pragma unroll
  for (int k = 0; k < 2; k++) {
    int e = topk_i[2 * t + k];
    int slot = 0;
    #pragma unroll
    for (int eid = 0; eid < NEXP; eid++) {
      unsigned long long mask = __ballot(e == eid);
      if (e == eid) {
        int leader = __ffsll((unsigned long long)mask) - 1;
        int cnt = __popcll(mask);
        int base = 0;
        if (lane == leader) base = atomicAdd(&fillc[eid], cnt);
        base = __shfl(base, leader, 64);
        int pos = __popcll(mask & ((1ULL << lane) - 1ULL));
        slot = offsets[eid] + base + pos;
      }
    }
    token_list[slot] = t;
    slot_of[2 * t + k] = slot;
  }
}

// ------- grouped GEMM: 128x128 tile, 32x32x16 MFMA, async LDS staging ------
// xcd = expert swizzle (blockIdx & 7 round-robins over 8 XCDs): each XCD's
// private L2 keeps its expert's whole B (4 MB) resident.
// LDS tiles unpadded [128][64]; global source XOR-swizzled per lane so the
// lane-linear global_load_lds scatter lands pre-swizzled; frag ds_read_b128
// hits the 8-lane/4-bank b128 floor with no extra conflicts (R3: counter=0).
template<bool GELU, bool GATHER, int NXN>
__global__ __launch_bounds__(256, 2) void gemm_kernel(
    const unsigned short* __restrict__ Abase,  // bf16 [*, K]
    const unsigned short* __restrict__ BT,     // bf16 [E][N][K]
    const float* __restrict__ bias,            // fp32 [E][N]
    unsigned short* __restrict__ Cout,         // bf16 [NASSIGN][N]
    const int* __restrict__ counts,
    const int* __restrict__ offsets,
    const int* __restrict__ token_list,
    int K, int N) {
  int flat = blockIdx.x;
  int e = flat & 7;          // xcd-local expert
  int q = flat >> 3;
  int n_idx = q % NXN;
  int mtile = q / NXN;
  int cnt = counts[e];
  if (mtile * 128 >= cnt) return;
  int rowbase = offsets[e];
  int n0 = n_idx * 128;
  int tid = threadIdx.x;
  int wid = tid >> 6, lane = tid & 63;

  __shared__ unsigned short As[128 * BK];
  __shared__ unsigned short Bs[128 * BK];

  // staging: wave w stages rows [32w, 32w+32), 4 instrs x (8 rows x 8 chunks)
  const unsigned short* asrc[4];
  const unsigned short* bsrc[4];
  #pragma unroll
  for (int j = 0; j < 4; j++) {
    int r = wid * 32 + j * 8 + (lane >> 3);  // tile row 0..127
    int p = lane & 7;                        // 16B chunk in lane-linear dest
    int swz = ((p ^ (r & 7)) * 8);           // source element offset in row
    long arow;
    if (GATHER) {
      int rl = mtile * 128 + r;
      int t = token_list[rowbase + min(rl, cnt - 1)];
      arow = (long)t * K;
    } else {
      int rr = rowbase + min(mtile * 128 + r, cnt - 1);
      arow = (long)rr * K;
    }
    asrc[j] = Abase + arow + swz;
    bsrc[j] = BT + ((long)e * N + n0 + r) * K + swz;
  }

  // wave tile: 64x64 via 2x2 frags of 32x32
  int wr = (wid >> 1) * 64, wc = (wid & 1) * 64;
  int l31 = lane & 31, lg = lane >> 5;

  // precomputed LDS frag offsets (k0-invariant)
  int aoff[2][4], boff[2][4];
  #pragma unroll
  for (int im = 0; im < 2; im++) {
    int r = wr + im * 32 + l31;
    #pragma unroll
    for (int kk = 0; kk < 4; kk++) {
      int c = kk * 2 + lg;
      aoff[im][kk] = r * BK + ((c ^ (r & 7)) * 8);
    }
  }
  #pragma unroll
  for (int in = 0; in < 2; in++) {
    int r = wc + in * 32 + l31;
    #pragma unroll
    for (int kk = 0; kk < 4; kk++) {
      int c = kk * 2 + lg;
      boff[in][kk] = r * BK + ((c ^ (r & 7)) * 8);
    }
  }

  floatx16 acc[2][2];
  #pragma unroll
  for (int im = 0; im < 2; im++)
    #pragma unroll
    for (int in = 0; in < 2; in++)
      #pragma unroll
      for (int j = 0; j < 16; j++) acc[im][in][j] = 0.f;

  for (int k0 = 0; k0 < K; k0 += BK) {
    #pragma unroll
    for (int j = 0; j < 4; j++) {
      int dst = (wid * 32 + j * 8) * BK;  // element offset of instr dest
      __builtin_amdgcn_global_load_lds((gbl_void*)(asrc[j] + k0),
                                       (lds_void*)&As[dst], 16, 0, 0);
      __builtin_amdgcn_global_load_lds((gbl_void*)(bsrc[j] + k0),
                                       (lds_void*)&Bs[dst], 16, 0, 0);
    }
    __syncthreads();
    #pragma unroll
    for (int kk = 0; kk < 4; kk++) {
      short8 a0 = *(const short8*)&As[aoff[0][kk]];
      short8 a1 = *(const short8*)&As[aoff[1][kk]];
      short8 b0 = *(const short8*)&Bs[boff[0][kk]];
      short8 b1 = *(const short8*)&Bs[boff[1][kk]];
      acc[0][0] = __builtin_amdgcn_mfma_f32_32x32x16_bf16(a0, b0, acc[0][0], 0, 0, 0);
      acc[0][1] = __builtin_amdgcn_mfma_f32_32x32x16_bf16(a0, b1, acc[0][1], 0, 0, 0);
      acc[1][0] = __builtin_amdgcn_mfma_f32_32x32x16_bf16(a1, b0, acc[1][0], 0, 0, 0);
      acc[1][1] = __builtin_amdgcn_mfma_f32_32x32x16_bf16(a1, b1, acc[1][1], 0, 0, 0);
    }
    __syncthreads();
  }

  // epilogue: C/D layout col=lane&31, row=(reg&3)+8*(reg>>2)+4*lg  [m74/m101]
  float bv[2];
  #pragma unroll
  for (int in = 0; in < 2; in++)
    bv[in] = bias[(long)e * N + n0 + wc + in * 32 + l31];
  #pragma unroll
  for (int im = 0; im < 2; im++) {
    #pragma unroll
    for (int reg = 0; reg < 16; reg++) {
      int rowf = (reg & 3) + 8 * (reg >> 2) + 4 * lg;
      int r = mtile * 128 + wr + im * 32 + rowf;
      if (r < cnt) {
        long rowoff = (long)(rowbase + r) * N;
        #pragma unroll
        for (int in = 0; in < 2; in++) {
          int col = n0 + wc + in * 32 + l31;
          float v = acc[im][in][reg] + bv[in];
          if (GELU) v = gelu_fast(v);
          Cout[rowoff + col] = f2bf(v);
        }
      }
    }
  }
}

// ---------------- combine: out[t] = w0*Y[s0] + w1*Y[s1] ----------------
__global__ void combine_kernel(const unsigned short* __restrict__ Yb,
                               const int* __restrict__ slot_of,
                               const float* __restrict__ topk_w,
                               float* __restrict__ out) {
  int idx = blockIdx.x * 256 + threadIdx.x;  // T * (D/8) threads
  int t = idx >> 7;
  int d = (idx & 127) * 8;
  int s0 = slot_of[2 * t], s1 = slot_of[2 * t + 1];
  float w0 = topk_w[2 * t], w1 = topk_w[2 * t + 1];
  short8 y0 = *(const short8*)(Yb + (long)s0 * DIM + d);
  short8 y1 = *(const short8*)(Yb + (long)s1 * DIM + d);
  float o[8];
  #pragma unroll
  for (int j = 0; j < 8; j++)
    o[j] = w0 * bf2f((unsigned short)y0[j]) + w1 * bf2f((unsigned short)y1[j]);
  float4 lo = {o[0], o[1], o[2], o[3]};
  float4 hi = {o[4], o[5], o[6], o[7]};
  float* op = out + (long)t * DIM + d;
  *(float4*)op = lo;
  *(float4*)(op + 4) = hi;
}

extern "C" void kernel_launch(void* const* d_in, const int* in_sizes, int n_in,
                              void* d_out, int out_size, void* d_ws, size_t ws_size,
                              hipStream_t stream) {
  const float* x  = (const float*)d_in[0];   // [T, D]
  const float* Wr = (const float*)d_in[1];   // [D, E]
  const float* br = (const float*)d_in[2];   // [E]
  const float* W1 = (const float*)d_in[3];   // [E, D, H]
  const float* b1 = (const float*)d_in[4];   // [E, H]
  const float* W2 = (const float*)d_in[5];   // [E, H, D]
  const float* b2 = (const float*)d_in[6];   // [E, D]
  float* out = (float*)d_out;                // [T*D] ++ [1] aux

  char* ws = (char*)d_ws;
  const long XB_OFF  = 0;                                   // T*D bf16
  const long W1T_OFF = XB_OFF  + (long)T_TOKENS * DIM * 2;  // E*H*D bf16
  const long W2T_OFF = W1T_OFF + (long)NEXP * DIM * HDIM * 2;
  const long HB_OFF  = W2T_OFF + (long)NEXP * DIM * HDIM * 2; // NASSIGN*H bf16
  const long YB_OFF  = HB_OFF  + (long)NASSIGN * HDIM * 2;    // NASSIGN*D bf16
  const long META_OFF = YB_OFF + (long)NASSIGN * DIM * 2;

  unsigned short* Xb  = (unsigned short*)(ws + XB_OFF);
  unsigned short* W1T = (unsigned short*)(ws + W1T_OFF);
  unsigned short* W2T = (unsigned short*)(ws + W2T_OFF);
  unsigned short* Hb  = (unsigned short*)(ws + HB_OFF);
  unsigned short* Yb  = (unsigned short*)(ws + YB_OFF);

  char* meta = ws + META_OFF;
  int*   counts    = (int*)(meta + 0);
  int*   offsets   = (int*)(meta + 32);
  int*   fillc     = (int*)(meta + 64);
  int*   topk_i    = (int*)(meta + 128);
  float* topk_w    = (float*)(meta + 128 + 65536);
  int*   token_list= (int*)(meta + 128 + 131072);
  int*   slot_of   = (int*)(meta + 128 + 196608);
  int*   pc_part   = (int*)(meta + 128 + 262144);           // [RBLOCKS][8]
  float* pp_part   = (float*)(meta + 128 + 262144 + 65536); // [RBLOCKS][8]

  // zero counters (ws is poisoned 0xAA before every timed call)
  hipMemsetAsync(meta, 0, 128, stream);

  // 1. weight layout transforms (both in one dispatch)
  transpose_convert2_kernel<<<8192, 256, 0, stream>>>(W1, W2, W1T, W2T);

  // 2. router (fp32, atomic-free, fused x->bf16)
  router_kernel<<<RBLOCKS, 256, 0, stream>>>(x, Wr, br, Xb, topk_i, topk_w,
                                             pc_part, pp_part);
  // 3. reduce partials + offsets + aux loss
  scan_aux_kernel<<<1, 256, 0, stream>>>(pc_part, pp_part, counts, offsets,
                                         out + (long)T_TOKENS * DIM);
  // 4. fill token lists
  fill_kernel<<<T_TOKENS / 256, 256, 0, stream>>>(topk_i, offsets, fillc,
                                                  token_list, slot_of);
  // 5. expert GEMM 1: H = gelu(X @ W1 + b1)   M=counts, N=2048, K=1024
  gemm_kernel<true, true, HDIM / 128><<<NEXP * 64 * (HDIM / 128), 256, 0, stream>>>(
      Xb, W1T, b1, Hb, counts, offsets, token_list, DIM, HDIM);
  // 6. expert GEMM 2: Y = H @ W2 + b2         M=counts, N=1024, K=2048
  gemm_kernel<false, false, DIM / 128><<<NEXP * 64 * (DIM / 128), 256, 0, stream>>>(
      Hb, W2T, b2, Yb, counts, offsets, nullptr, HDIM, DIM);
  // 7. combine
  combine_kernel<<<T_TOKENS * (DIM / 8) / 256, 256, 0, stream>>>(
      Yb, slot_of, topk_w, out);
}

// Round 5
// 424.318 us; speedup vs baseline: 3.2627x; 1.0672x over previous
//
#include <hip/hip_runtime.h>
#include <math.h>

// Problem constants (B=4,S=2048,D=1024,H=2048,E=8, top-2)
#define T_TOKENS 8192
#define DIM      1024
#define HDIM     2048
#define NEXP     8
#define NASSIGN  16384   // T_TOKENS * 2
#define RTOK     16      // tokens per router block
#define RBLOCKS  (T_TOKENS / RTOK)
#define BK       64      // GEMM K-tile
#define SWSTRIDE 1028    // router sW leading dim (breaks 8-way store conflict)

typedef __attribute__((ext_vector_type(8))) short short8;
typedef __attribute__((ext_vector_type(4))) float floatx4;
typedef __attribute__((address_space(3))) void lds_void;
typedef const __attribute__((address_space(1))) void gbl_void;

__device__ __forceinline__ unsigned short f2bf(float f) {
  unsigned u = __float_as_uint(f);
  u += 0x7fffu + ((u >> 16) & 1u);   // RNE
  return (unsigned short)(u >> 16);
}
__device__ __forceinline__ float bf2f(unsigned short h) {
  return __uint_as_float(((unsigned)h) << 16);
}

// fast GELU: v * sigmoid(1.5958*(v + 0.044715 v^3)); max abs err ~1e-3 vs erf
__device__ __forceinline__ float gelu_fast(float v) {
  float u = 1.5957691216057308f * v * fmaf(0.044715f * v, v, 1.0f);
  return v / (1.f + __expf(-u));
}

// ------- fused transpose+convert: W1 and W2, [E][R][C] fp32 -> [E][C][R] bf16
__global__ __launch_bounds__(256) void transpose_convert2_kernel(
    const float* __restrict__ W1, const float* __restrict__ W2,
    unsigned short* __restrict__ W1T, unsigned short* __restrict__ W2T) {
  __shared__ float tile[64][65];
  int b = blockIdx.x;
  const float* inp; unsigned short* outp; int R, C, r0, c0;
  if (b < 4096) {                       // W1: R=1024, C=2048; 512 tiles/expert
    int e = b >> 9, t = b & 511;
    R = DIM; C = HDIM;
    c0 = (t & 31) * 64; r0 = (t >> 5) * 64;
    long eb = (long)e * R * C;
    inp = W1 + eb; outp = W1T + eb;
  } else {                              // W2: R=2048, C=1024
    int bb = b - 4096;
    int e = bb >> 9, t = bb & 511;
    R = HDIM; C = DIM;
    c0 = (t & 15) * 64; r0 = (t >> 4) * 64;
    long eb = (long)e * R * C;
    inp = W2 + eb; outp = W2T + eb;
  }
  int tid = threadIdx.x;
  int rr = tid >> 4, c4 = (tid & 15) * 4;
  #pragma unroll
  for (int i = 0; i < 4; i++) {
    float4 v = *(const float4*)(inp + (long)(r0 + rr + i * 16) * C + c0 + c4);
    tile[rr + i * 16][c4 + 0] = v.x;
    tile[rr + i * 16][c4 + 1] = v.y;
    tile[rr + i * 16][c4 + 2] = v.z;
    tile[rr + i * 16][c4 + 3] = v.w;
  }
  __syncthreads();
  int rq = (tid & 15) * 4, cc = tid >> 4;
  #pragma unroll
  for (int i = 0; i < 4; i++) {
    int c = cc + i * 16;
    ushort4 o;
    o.x = f2bf(tile[rq + 0][c]);
    o.y = f2bf(tile[rq + 1][c]);
    o.z = f2bf(tile[rq + 2][c]);
    o.w = f2bf(tile[rq + 3][c]);
    *(ushort4*)(outp + (long)(c0 + c) * R + r0 + rq) = o;
  }
}

// ------- router: fp32 logits, fused x->bf16 convert, no global atomics -----
__global__ __launch_bounds__(256) void router_kernel(
    const float* __restrict__ x, const float* __restrict__ Wr,
    const float* __restrict__ br, unsigned short* __restrict__ Xb,
    int* __restrict__ topk_i, float* __restrict__ topk_w,
    int* __restrict__ pc_partial,      // [RBLOCKS][NEXP]
    float* __restrict__ pp_partial) {  // [RBLOCKS][NEXP]
  __shared__ float sW[NEXP * SWSTRIDE];  // sW[e*SWSTRIDE + d]
  __shared__ float sP[4][NEXP];
  __shared__ int   sC[4][NEXP];
  int tid = threadIdx.x;
  for (int i = tid; i < NEXP * DIM; i += 256)   // coalesced load, spread banks
    sW[(i & 7) * SWSTRIDE + (i >> 3)] = Wr[i];
  __syncthreads();
  int wid = tid >> 6, lane = tid & 63;
  float pacc[NEXP]; int cacc[NEXP];
  #pragma unroll
  for (int e = 0; e < NEXP; e++) { pacc[e] = 0.f; cacc[e] = 0; }
  #pragma unroll
  for (int it = 0; it < 4; it++) {
    int t = blockIdx.x * RTOK + wid * 4 + it;
    const float* xp = x + (long)t * DIM;
    unsigned short* xbp = Xb + (long)t * DIM;
    float acc[NEXP];
    #pragma unroll
    for (int e = 0; e < NEXP; e++) acc[e] = 0.f;
    #pragma unroll
    for (int i = 0; i < 4; i++) {
      int off = i * 256 + lane * 4;
      float4 v = *(const float4*)(xp + off);
      ushort4 o;
      o.x = f2bf(v.x); o.y = f2bf(v.y); o.z = f2bf(v.z); o.w = f2bf(v.w);
      *(ushort4*)(xbp + off) = o;
      #pragma unroll
      for (int e = 0; e < NEXP; e++) {
        float4 w = *(const float4*)&sW[e * SWSTRIDE + off];
        acc[e] += v.x * w.x + v.y * w.y + v.z * w.z + v.w * w.w;
      }
    }
    #pragma unroll
    for (int e = 0; e < NEXP; e++) {
      #pragma unroll
      for (int off = 32; off; off >>= 1) acc[e] += __shfl_xor(acc[e], off, 64);
    }
    if (lane == 0) {
      float l[NEXP];
      #pragma unroll
      for (int e = 0; e < NEXP; e++) l[e] = acc[e] + br[e];
      float mx = l[0];
      #pragma unroll
      for (int e = 1; e < NEXP; e++) mx = fmaxf(mx, l[e]);
      float p[NEXP], s = 0.f;
      #pragma unroll
      for (int e = 0; e < NEXP; e++) { p[e] = __expf(l[e] - mx); s += p[e]; }
      float inv = 1.f / s;
      #pragma unroll
      for (int e = 0; e < NEXP; e++) p[e] *= inv;
      // top-2, lowest index wins ties (matches lax.top_k)
      int i1 = 0;
      #pragma unroll
      for (int e = 1; e < NEXP; e++) if (l[e] > l[i1]) i1 = e;
      int i2 = (i1 == 0) ? 1 : 0;
      #pragma unroll
      for (int e = 0; e < NEXP; e++)
        if (e != i1 && l[e] > l[i2]) i2 = e;
      float s2 = fmaxf(p[i1] + p[i2], 1e-9f);
      topk_i[2 * t] = i1; topk_i[2 * t + 1] = i2;
      topk_w[2 * t] = p[i1] / s2; topk_w[2 * t + 1] = p[i2] / s2;
      #pragma unroll
      for (int e = 0; e < NEXP; e++) {
        pacc[e] += p[e];
        cacc[e] += (e == i1 || e == i2) ? 1 : 0;
      }
    }
  }
  if (lane == 0) {
    #pragma unroll
    for (int e = 0; e < NEXP; e++) { sP[wid][e] = pacc[e]; sC[wid][e] = cacc[e]; }
  }
  __syncthreads();
  if (tid < NEXP) {
    float ps = 0.f; int cs = 0;
    #pragma unroll
    for (int w = 0; w < 4; w++) { ps += sP[w][tid]; cs += sC[w][tid]; }
    pp_partial[blockIdx.x * NEXP + tid] = ps;
    pc_partial[blockIdx.x * NEXP + tid] = cs;
  }
}

// ------- reduce partials -> counts/offsets, compute aux loss ----------
__global__ __launch_bounds__(256) void scan_aux_kernel(
    const int* __restrict__ pc_partial, const float* __restrict__ pp_partial,
    int* __restrict__ counts, int* __restrict__ offsets,
    float* __restrict__ aux_out) {
  __shared__ int sc[32][NEXP];
  __shared__ float sp[32][NEXP];
  int tid = threadIdx.x;
  int e = tid & 7, chunk = tid >> 3;  // 32 chunks of blocks
  int cs = 0; float ps = 0.f;
  for (int b = chunk; b < RBLOCKS; b += 32) {
    cs += pc_partial[b * NEXP + e];
    ps += pp_partial[b * NEXP + e];
  }
  sc[chunk][e] = cs; sp[chunk][e] = ps;
  __syncthreads();
  if (tid == 0) {
    int cnt[NEXP]; float prs[NEXP];
    #pragma unroll
    for (int ee = 0; ee < NEXP; ee++) { cnt[ee] = 0; prs[ee] = 0.f; }
    for (int c = 0; c < 32; c++)
      #pragma unroll
      for (int ee = 0; ee < NEXP; ee++) { cnt[ee] += sc[c][ee]; prs[ee] += sp[c][ee]; }
    int total = 0;
    #pragma unroll
    for (int ee = 0; ee < NEXP; ee++) total += cnt[ee];
    float inv_total = 1.f / (float)(total > 0 ? total : 1);
    int off = 0; float aux = 0.f;
    #pragma unroll
    for (int ee = 0; ee < NEXP; ee++) {
      counts[ee] = cnt[ee];
      offsets[ee] = off; off += cnt[ee];
      float importance = prs[ee] / (float)T_TOKENS;
      float load = (float)cnt[ee] * inv_total;
      aux += importance * load;
    }
    *aux_out = (float)NEXP * aux;
  }
}

// ---------------- fill per-expert token lists (ballot-batched atomics) -----
__global__ void fill_kernel(const int* __restrict__ topk_i,
                            const int* __restrict__ offsets,
                            int* __restrict__ fillc,
                            int* __restrict__ token_list,
                            int* __restrict__ slot_of) {
  int t = blockIdx.x * 256 + threadIdx.x;
  int lane = threadIdx.x & 63;
  #pragma unroll
  for (int k = 0; k < 2; k++) {
    int e = topk_i[2 * t + k];
    int slot = 0;
    #pragma unroll
    for (int eid = 0; eid < NEXP; eid++) {
      unsigned long long mask = __ballot(e == eid);
      if (e == eid) {
        int leader = __ffsll((unsigned long long)mask) - 1;
        int cnt = __popcll(mask);
        int base = 0;
        if (lane == leader) base = atomicAdd(&fillc[eid], cnt);
        base = __shfl(base, leader, 64);
        int pos = __popcll(mask & ((1ULL << lane) - 1ULL));
        slot = offsets[eid] + base + pos;
      }
    }
    token_list[slot] = t;
    slot_of[2 * t + k] = slot;
  }
}

// ------- grouped GEMM: 128x128 tile, 16x16x32 MFMA, async LDS staging ------
// xcd = expert swizzle (blockIdx & 7 round-robins over 8 XCDs): each XCD's
// private L2 keeps its expert's whole B (4 MB) resident.
// LDS tiles unpadded [128][64]; global source XOR-swizzled per lane so the
// lane-linear global_load_lds scatter lands pre-swizzled; 16x16 frag pattern
// (16 rows x 4 chunk-cols per wave read) measured conflict-free (R3: 0;
// 32x32 pattern measured 8.65M extra cycles in R4 -> reverted).
template<bool GELU, bool GATHER, int NXN>
__global__ __launch_bounds__(256, 3) void gemm_kernel(
    const unsigned short* __restrict__ Abase,  // bf16 [*, K]
    const unsigned short* __restrict__ BT,     // bf16 [E][N][K]
    const float* __restrict__ bias,            // fp32 [E][N]
    unsigned short* __restrict__ Cout,         // bf16 [NASSIGN][N]
    const int* __restrict__ counts,
    const int* __restrict__ offsets,
    const int* __restrict__ token_list,
    int K, int N) {
  int flat = blockIdx.x;
  int e = flat & 7;          // xcd-local expert
  int q = flat >> 3;
  int n_idx = q % NXN;
  int mtile = q / NXN;
  int cnt = counts[e];
  if (mtile * 128 >= cnt) return;
  int rowbase = offsets[e];
  int n0 = n_idx * 128;
  int tid = threadIdx.x;
  int wid = tid >> 6, lane = tid & 63;

  __shared__ unsigned short As[128 * BK];
  __shared__ unsigned short Bs[128 * BK];

  // staging: wave w stages rows [32w, 32w+32), 4 instrs x (8 rows x 8 chunks)
  const unsigned short* asrc[4];
  const unsigned short* bsrc[4];
  #pragma unroll
  for (int j = 0; j < 4; j++) {
    int r = wid * 32 + j * 8 + (lane >> 3);  // tile row 0..127
    int p = lane & 7;                        // 16B chunk in lane-linear dest
    int swz = ((p ^ (r & 7)) * 8);           // source element offset in row
    long arow;
    if (GATHER) {
      int rl = mtile * 128 + r;
      int t = token_list[rowbase + min(rl, cnt - 1)];
      arow = (long)t * K;
    } else {
      int rr = rowbase + min(mtile * 128 + r, cnt - 1);
      arow = (long)rr * K;
    }
    asrc[j] = Abase + arow + swz;
    bsrc[j] = BT + ((long)e * N + n0 + r) * K + swz;
  }

  // wave tile: 64x64 via 4x4 frags of 16x16
  int wr = (wid >> 1) * 64, wc = (wid & 1) * 64;
  int lr = lane & 15, lq = lane >> 4;

  // precomputed LDS frag offsets (k0-invariant)
  int aoff[4][2], boff[4][2];
  #pragma unroll
  for (int im = 0; im < 4; im++) {
    int r = wr + im * 16 + lr;
    #pragma unroll
    for (int kk = 0; kk < 2; kk++) {
      int c = kk * 4 + lq;
      aoff[im][kk] = r * BK + ((c ^ (r & 7)) * 8);
    }
  }
  #pragma unroll
  for (int in = 0; in < 4; in++) {
    int r = wc + in * 16 + lr;
    #pragma unroll
    for (int kk = 0; kk < 2; kk++) {
      int c = kk * 4 + lq;
      boff[in][kk] = r * BK + ((c ^ (r & 7)) * 8);
    }
  }

  floatx4 zero = {0.f, 0.f, 0.f, 0.f};
  floatx4 acc[4][4];
  #pragma unroll
  for (int im = 0; im < 4; im++)
    #pragma unroll
    for (int in = 0; in < 4; in++) acc[im][in] = zero;

  for (int k0 = 0; k0 < K; k0 += BK) {
    #pragma unroll
    for (int j = 0; j < 4; j++) {
      int dst = (wid * 32 + j * 8) * BK;  // element offset of instr dest
      __builtin_amdgcn_global_load_lds((gbl_void*)(asrc[j] + k0),
                                       (lds_void*)&As[dst], 16, 0, 0);
      __builtin_amdgcn_global_load_lds((gbl_void*)(bsrc[j] + k0),
                                       (lds_void*)&Bs[dst], 16, 0, 0);
    }
    __syncthreads();
    #pragma unroll
    for (int kk = 0; kk < 2; kk++) {
      short8 af[4], bf[4];
      #pragma unroll
      for (int im = 0; im < 4; im++) af[im] = *(const short8*)&As[aoff[im][kk]];
      #pragma unroll
      for (int in = 0; in < 4; in++) bf[in] = *(const short8*)&Bs[boff[in][kk]];
      #pragma unroll
      for (int im = 0; im < 4; im++)
        #pragma unroll
        for (int in = 0; in < 4; in++)
          acc[im][in] = __builtin_amdgcn_mfma_f32_16x16x32_bf16(
              af[im], bf[in], acc[im][in], 0, 0, 0);
    }
    __syncthreads();
  }

  // epilogue: D layout col=lane&15, row=(lane>>4)*4+reg  [m89/m91]
  float bv[4];
  #pragma unroll
  for (int in = 0; in < 4; in++)
    bv[in] = bias[(long)e * N + n0 + wc + in * 16 + lr];
  #pragma unroll
  for (int im = 0; im < 4; im++) {
    int rbase = mtile * 128 + wr + im * 16 + lq * 4;
    #pragma unroll
    for (int j = 0; j < 4; j++) {
      int r = rbase + j;
      if (r < cnt) {
        long rowoff = (long)(rowbase + r) * N;
        #pragma unroll
        for (int in = 0; in < 4; in++) {
          int col = n0 + wc + in * 16 + lr;
          float v = acc[im][in][j] + bv[in];
          if (GELU) v = gelu_fast(v);
          Cout[rowoff + col] = f2bf(v);
        }
      }
    }
  }
}

// ---------------- combine: out[t] = w0*Y[s0] + w1*Y[s1] ----------------
__global__ void combine_kernel(const unsigned short* __restrict__ Yb,
                               const int* __restrict__ slot_of,
                               const float* __restrict__ topk_w,
                               float* __restrict__ out) {
  int idx = blockIdx.x * 256 + threadIdx.x;  // T * (D/8) threads
  int t = idx >> 7;
  int d = (idx & 127) * 8;
  int s0 = slot_of[2 * t], s1 = slot_of[2 * t + 1];
  float w0 = topk_w[2 * t], w1 = topk_w[2 * t + 1];
  short8 y0 = *(const short8*)(Yb + (long)s0 * DIM + d);
  short8 y1 = *(const short8*)(Yb + (long)s1 * DIM + d);
  float o[8];
  #pragma unroll
  for (int j = 0; j < 8; j++)
    o[j] = w0 * bf2f((unsigned short)y0[j]) + w1 * bf2f((unsigned short)y1[j]);
  float4 lo = {o[0], o[1], o[2], o[3]};
  float4 hi = {o[4], o[5], o[6], o[7]};
  float* op = out + (long)t * DIM + d;
  *(float4*)op = lo;
  *(float4*)(op + 4) = hi;
}

extern "C" void kernel_launch(void* const* d_in, const int* in_sizes, int n_in,
                              void* d_out, int out_size, void* d_ws, size_t ws_size,
                              hipStream_t stream) {
  const float* x  = (const float*)d_in[0];   // [T, D]
  const float* Wr = (const float*)d_in[1];   // [D, E]
  const float* br = (const float*)d_in[2];   // [E]
  const float* W1 = (const float*)d_in[3];   // [E, D, H]
  const float* b1 = (const float*)d_in[4];   // [E, H]
  const float* W2 = (const float*)d_in[5];   // [E, H, D]
  const float* b2 = (const float*)d_in[6];   // [E, D]
  float* out = (float*)d_out;                // [T*D] ++ [1] aux

  char* ws = (char*)d_ws;
  const long XB_OFF  = 0;                                   // T*D bf16
  const long W1T_OFF = XB_OFF  + (long)T_TOKENS * DIM * 2;  // E*H*D bf16
  const long W2T_OFF = W1T_OFF + (long)NEXP * DIM * HDIM * 2;
  const long HB_OFF  = W2T_OFF + (long)NEXP * DIM * HDIM * 2; // NASSIGN*H bf16
  const long YB_OFF  = HB_OFF  + (long)NASSIGN * HDIM * 2;    // NASSIGN*D bf16
  const long META_OFF = YB_OFF + (long)NASSIGN * DIM * 2;

  unsigned short* Xb  = (unsigned short*)(ws + XB_OFF);
  unsigned short* W1T = (unsigned short*)(ws + W1T_OFF);
  unsigned short* W2T = (unsigned short*)(ws + W2T_OFF);
  unsigned short* Hb  = (unsigned short*)(ws + HB_OFF);
  unsigned short* Yb  = (unsigned short*)(ws + YB_OFF);

  char* meta = ws + META_OFF;
  int*   counts    = (int*)(meta + 0);
  int*   offsets   = (int*)(meta + 32);
  int*   fillc     = (int*)(meta + 64);
  int*   topk_i    = (int*)(meta + 128);
  float* topk_w    = (float*)(meta + 128 + 65536);
  int*   token_list= (int*)(meta + 128 + 131072);
  int*   slot_of   = (int*)(meta + 128 + 196608);
  int*   pc_part   = (int*)(meta + 128 + 262144);           // [RBLOCKS][8]
  float* pp_part   = (float*)(meta + 128 + 262144 + 65536); // [RBLOCKS][8]

  // zero counters (ws is poisoned 0xAA before every timed call)
  hipMemsetAsync(meta, 0, 128, stream);

  // 1. weight layout transforms (both in one dispatch)
  transpose_convert2_kernel<<<8192, 256, 0, stream>>>(W1, W2, W1T, W2T);

  // 2. router (fp32, atomic-free, fused x->bf16)
  router_kernel<<<RBLOCKS, 256, 0, stream>>>(x, Wr, br, Xb, topk_i, topk_w,
                                             pc_part, pp_part);
  // 3. reduce partials + offsets + aux loss
  scan_aux_kernel<<<1, 256, 0, stream>>>(pc_part, pp_part, counts, offsets,
                                         out + (long)T_TOKENS * DIM);
  // 4. fill token lists
  fill_kernel<<<T_TOKENS / 256, 256, 0, stream>>>(topk_i, offsets, fillc,
                                                  token_list, slot_of);
  // 5. expert GEMM 1: H = gelu(X @ W1 + b1)   M=counts, N=2048, K=1024
  gemm_kernel<true, true, HDIM / 128><<<NEXP * 64 * (HDIM / 128), 256, 0, stream>>>(
      Xb, W1T, b1, Hb, counts, offsets, token_list, DIM, HDIM);
  // 6. expert GEMM 2: Y = H @ W2 + b2         M=counts, N=1024, K=2048
  gemm_kernel<false, false, DIM / 128><<<NEXP * 64 * (DIM / 128), 256, 0, stream>>>(
      Hb, W2T, b2, Yb, counts, offsets, nullptr, HDIM, DIM);
  // 7. combine
  combine_kernel<<<T_TOKENS * (DIM / 8) / 256, 256, 0, stream>>>(
      Yb, slot_of, topk_w, out);
}